// Round 2
// baseline (331.273 us; speedup 1.0000x reference)
//
#include <hip/hip_runtime.h>
#include <hip/hip_bf16.h>
#include <math.h>

#define N_  128
#define D_  512
#define L_  512
#define K_  512
#define M_  (N_*D_)   // 65536

typedef __bf16 bf16x8 __attribute__((ext_vector_type(8)));
typedef float  f32x4  __attribute__((ext_vector_type(4)));
typedef unsigned short ushort_t;

// ---------------------------------------------------------------------------
// Kernel 1: bf16 DFT basis (Bc/Bs, [k][l], symmetric) + separable window
// tables: P=a*e, Q=-(1-a)*e, e=exp(sigma/511), C[l]=cos(2*pi*l/511).
// Basis reduced exactly via (k*l mod 511), fp32 sincos.
// ---------------------------------------------------------------------------
__global__ void basis_kernel(const float* __restrict__ a,
                             const float* __restrict__ sigma,
                             ushort_t* __restrict__ Bc,
                             ushort_t* __restrict__ Bs,
                             float* __restrict__ P,
                             float* __restrict__ Q,
                             float* __restrict__ C) {
    int idx = blockIdx.x * 256 + threadIdx.x;   // 0 .. 512*512-1
    int r = idx >> 9;    // k
    int c = idx & 511;   // l
    unsigned m = (unsigned)(r * c) % 511u;      // exact periodic reduction
    const float w0 = 6.283185307179586f / 511.0f;
    float sn, cs;
    sincosf((float)m * w0, &sn, &cs);
    __hip_bfloat16 bc = __float2bfloat16(cs);
    __hip_bfloat16 bs = __float2bfloat16(sn);
    ushort_t uc, us;
    __builtin_memcpy(&uc, &bc, 2);
    __builtin_memcpy(&us, &bs, 2);
    Bc[idx] = uc;
    Bs[idx] = us;
    if (idx < 512) {
        float e = expf(sigma[idx] * (1.0f / 511.0f));
        P[idx] = a[idx] * e;
        Q[idx] = -(1.0f - a[idx]) * e;
        C[idx] = cosf((float)idx * w0);
    }
}

static __device__ __forceinline__ unsigned pack_bf16x2(float lo, float hi) {
    __hip_bfloat162 h = __float22bfloat162_rn(make_float2(lo, hi));
    unsigned u;
    __builtin_memcpy(&u, &h, 4);
    return u;   // lo in low 16 bits -> memory order [lo, hi]
}

static __device__ __forceinline__ void load_lds_128(const void* g, void* l) {
    __builtin_amdgcn_global_load_lds(
        (const __attribute__((address_space(1))) unsigned int*)g,
        (__attribute__((address_space(3))) unsigned int*)l,
        16, 0, 0);
}

// ---------------------------------------------------------------------------
// Kernel 2 (FUSED): prep folded into the GEMM's A-staging.
//  - A: reg-staged from fp32 x; window (P + Q*C[l]) applied in-flight,
//    packed to bf16, ds_write_b128 to XOR-swizzled LDS (same involution as
//    the fragment reads). T14 split: loads issued BEFORE the MFMA phase,
//    ds_writes AFTER (HBM latency hides under 32 MFMAs).
//  - B (Bc/Bs): unchanged global_load_lds(16B) with pre-swizzled source.
//  - 2-phase double-buffered pipeline, one barrier/iter.
//  - XCD-chunked block swizzle: the 4 N-sibling blocks of each A-panel run
//    consecutively on the SAME XCD -> A fp32 reuse is an L2 hit, so the 4x
//    logical A redundancy does not become HBM traffic.
// ---------------------------------------------------------------------------
__global__ __launch_bounds__(256, 2)
void dft_gemm4(const float* __restrict__ x,
               const ushort_t* __restrict__ Bc,
               const ushort_t* __restrict__ Bs,
               const float* __restrict__ P,
               const float* __restrict__ Q,
               const float* __restrict__ C,
               float* __restrict__ out) {
    // [2] double buffers, each 128x32 bf16 = 8 KB -> 48 KB total
    __shared__ ushort_t sA [2 * 128 * 32];
    __shared__ ushort_t sBc[2 * 128 * 32];
    __shared__ ushort_t sBs[2 * 128 * 32];

    // XCD-chunked bijection (2048 = 8 * 256, evenly divisible -> safe):
    // XCD j (= bhw & 7) gets contiguous wg range -> same-mg siblings adjacent.
    const int bhw = blockIdx.x;
    const int wg  = (bhw & 7) * 256 + (bhw >> 3);
    const int ng  = wg & 3;
    const int mg  = wg >> 2;
    const int m0  = mg * 128;
    const int n0  = ng * 128;

    const int tid  = threadIdx.x;
    const int w    = tid >> 6;
    const int lane = tid & 63;

    // ---- A fused staging mapping: thread -> rows r0, r0+64, k-chunk c ----
    const int ar0 = tid >> 2;                 // 0..63
    const int ac  = tid & 3;                  // logical 8-elem k-chunk
    const int ar1 = ar0 + 64;
    const int apc = ac ^ ((ar0 >> 1) & 3);    // phys chunk (same for ar1)
    const int d0  = m0 & (D_ - 1);

    const float p0 = P[d0 + ar0], q0 = Q[d0 + ar0];
    const float p1 = P[d0 + ar1], q1 = Q[d0 + ar1];

    const float* xr0 = x + (size_t)(m0 + ar0) * L_ + ac * 8;
    const float* xr1 = x + (size_t)(m0 + ar1) * L_ + ac * 8;
    const float* Cc  = C + ac * 8;

    ushort_t* aD0 = sA + ar0 * 32 + apc * 8;  // + buf*4096
    ushort_t* aD1 = sA + ar1 * 32 + apc * 8;

    // ---- B staging via global_load_lds (pre-swizzled per-lane source) ----
    const int br0 = tid >> 2;
    const int bq0 = (tid & 3) ^ ((br0 >> 1) & 3);
    const int br1 = (256 + tid) >> 2;
    const int bq1 = ((256 + tid) & 3) ^ ((br1 >> 1) & 3);

    const ushort_t* bcS0 = Bc + (size_t)(n0 + br0) * L_ + bq0 * 8;
    const ushort_t* bcS1 = Bc + (size_t)(n0 + br1) * L_ + bq1 * 8;
    const ushort_t* bsS0 = Bs + (size_t)(n0 + br0) * L_ + bq0 * 8;
    const ushort_t* bsS1 = Bs + (size_t)(n0 + br1) * L_ + bq1 * 8;

    const int wm = w >> 1, wn = w & 1;
    const int ml = lane & 15, quad = lane >> 4;

    int aOff[4], bOff[4];
#pragma unroll
    for (int mi = 0; mi < 4; ++mi) {
        int ar = wm * 64 + mi * 16 + ml;
        int pc = quad ^ ((ar >> 1) & 3);
        aOff[mi] = ar * 32 + pc * 8;
    }
#pragma unroll
    for (int ni = 0; ni < 4; ++ni) {
        int br = wn * 64 + ni * 16 + ml;
        int pc = quad ^ ((br >> 1) & 3);
        bOff[ni] = br * 32 + pc * 8;
    }

    f32x4 acc_c[4][4], acc_s[4][4];
    const f32x4 zero = {0.f, 0.f, 0.f, 0.f};
#pragma unroll
    for (int mi = 0; mi < 4; ++mi)
#pragma unroll
        for (int ni = 0; ni < 4; ++ni) { acc_c[mi][ni] = zero; acc_s[mi][ni] = zero; }

#define STAGE_B(buf, kk)                                                      \
    do {                                                                      \
        const int bo_ = (buf) * 4096;                                         \
        load_lds_128(bcS0 + (kk), sBc + bo_ + w * 512);                       \
        load_lds_128(bcS1 + (kk), sBc + bo_ + 2048 + w * 512);                \
        load_lds_128(bsS0 + (kk), sBs + bo_ + w * 512);                       \
        load_lds_128(bsS1 + (kk), sBs + bo_ + 2048 + w * 512);                \
    } while (0)

    // window + bf16-pack + swizzled ds_write of one A k-tile (2 rows/thread)
    auto writeA = [&](int buf, float4 v00, float4 v01, float4 v10, float4 v11,
                      float4 cv0, float4 cv1) {
        int bo = buf * 4096;
        // row ar0
        float w0a = fmaf(q0, cv0.x, p0), w0b = fmaf(q0, cv0.y, p0);
        float w0c = fmaf(q0, cv0.z, p0), w0d = fmaf(q0, cv0.w, p0);
        float w0e = fmaf(q0, cv1.x, p0), w0f = fmaf(q0, cv1.y, p0);
        float w0g = fmaf(q0, cv1.z, p0), w0h = fmaf(q0, cv1.w, p0);
        int4 s0;
        s0.x = (int)pack_bf16x2(v00.x * w0a, v00.y * w0b);
        s0.y = (int)pack_bf16x2(v00.z * w0c, v00.w * w0d);
        s0.z = (int)pack_bf16x2(v01.x * w0e, v01.y * w0f);
        s0.w = (int)pack_bf16x2(v01.z * w0g, v01.w * w0h);
        *(int4*)(aD0 + bo) = s0;
        // row ar1
        float w1a = fmaf(q1, cv0.x, p1), w1b = fmaf(q1, cv0.y, p1);
        float w1c = fmaf(q1, cv0.z, p1), w1d = fmaf(q1, cv0.w, p1);
        float w1e = fmaf(q1, cv1.x, p1), w1f = fmaf(q1, cv1.y, p1);
        float w1g = fmaf(q1, cv1.z, p1), w1h = fmaf(q1, cv1.w, p1);
        int4 s1;
        s1.x = (int)pack_bf16x2(v10.x * w1a, v10.y * w1b);
        s1.y = (int)pack_bf16x2(v10.z * w1c, v10.w * w1d);
        s1.z = (int)pack_bf16x2(v11.x * w1e, v11.y * w1f);
        s1.w = (int)pack_bf16x2(v11.z * w1g, v11.w * w1h);
        *(int4*)(aD1 + bo) = s1;
    };

    auto compute_tile = [&](int buf) {
        const int bo = buf * 4096;
        bf16x8 af[4], bcf[4], bsf[4];
#pragma unroll
        for (int mi = 0; mi < 4; ++mi)
            af[mi] = *(const bf16x8*)&sA[bo + aOff[mi]];
#pragma unroll
        for (int ni = 0; ni < 4; ++ni) {
            bcf[ni] = *(const bf16x8*)&sBc[bo + bOff[ni]];
            bsf[ni] = *(const bf16x8*)&sBs[bo + bOff[ni]];
        }
#pragma unroll
        for (int mi = 0; mi < 4; ++mi)
#pragma unroll
            for (int ni = 0; ni < 4; ++ni) {
                acc_c[mi][ni] = __builtin_amdgcn_mfma_f32_16x16x32_bf16(
                    af[mi], bcf[ni], acc_c[mi][ni], 0, 0, 0);
                acc_s[mi][ni] = __builtin_amdgcn_mfma_f32_16x16x32_bf16(
                    af[mi], bsf[ni], acc_s[mi][ni], 0, 0, 0);
            }
    };

    // ---- prologue: tile 0 -> buf 0 ----
    float4 a00 = *(const float4*)(xr0 + 0);
    float4 a01 = *(const float4*)(xr0 + 4);
    float4 a10 = *(const float4*)(xr1 + 0);
    float4 a11 = *(const float4*)(xr1 + 4);
    float4 cv0 = *(const float4*)(Cc + 0);
    float4 cv1 = *(const float4*)(Cc + 4);
    STAGE_B(0, 0);
    writeA(0, a00, a01, a10, a11, cv0, cv1);
    __syncthreads();

    int cur = 0;
    for (int kk = 32; kk < L_; kk += 32) {
        // issue next-tile A loads FIRST (latency hides under MFMA phase)
        a00 = *(const float4*)(xr0 + kk);
        a01 = *(const float4*)(xr0 + kk + 4);
        a10 = *(const float4*)(xr1 + kk);
        a11 = *(const float4*)(xr1 + kk + 4);
        cv0 = *(const float4*)(Cc + kk);
        cv1 = *(const float4*)(Cc + kk + 4);
        STAGE_B(cur ^ 1, kk);       // B loads for next tile (vmcnt, async)
        compute_tile(cur);          // ds_read + 32 MFMA on current buffer
        writeA(cur ^ 1, a00, a01, a10, a11, cv0, cv1);  // write-late (T14)
        __syncthreads();            // drains vmcnt + lgkm; buffers swap
        cur ^= 1;
    }
    compute_tile(cur);              // last k-tile

#undef STAGE_B

    // C/D layout: col = lane&15, row = quad*4 + reg (m89/m91-verified)
#pragma unroll
    for (int mi = 0; mi < 4; ++mi)
#pragma unroll
        for (int ni = 0; ni < 4; ++ni) {
#pragma unroll
            for (int r = 0; r < 4; ++r) {
                float cv = acc_c[mi][ni][r];
                float sv = acc_s[mi][ni][r];
                int row = m0 + wm * 64 + mi * 16 + quad * 4 + r;
                int col = n0 + wn * 64 + ni * 16 + ml;
                out[(size_t)row * K_ + col] = sqrtf(cv * cv + sv * sv);
            }
        }
}

extern "C" void kernel_launch(void* const* d_in, const int* in_sizes, int n_in,
                              void* d_out, int out_size, void* d_ws, size_t ws_size,
                              hipStream_t stream) {
    (void)in_sizes; (void)n_in; (void)out_size; (void)ws_size;
    const float* x     = (const float*)d_in[0];
    const float* a     = (const float*)d_in[1];
    const float* sigma = (const float*)d_in[2];
    float* out = (float*)d_out;

    // ws: Bc (512KB) | Bs (512KB) | P (2KB) | Q (2KB) | C (2KB)
    ushort_t* Bc = (ushort_t*)d_ws;
    ushort_t* Bs = Bc + 512 * 512;
    float*    P  = (float*)(Bs + 512 * 512);
    float*    Q  = P + 512;
    float*    C  = Q + 512;

    basis_kernel<<<dim3(1024), dim3(256), 0, stream>>>(a, sigma, Bc, Bs, P, Q, C);
    dft_gemm4<<<dim3(2048), dim3(256), 0, stream>>>(x, Bc, Bs, P, Q, C, out);
}

// Round 3
// 267.793 us; speedup vs baseline: 1.2370x; 1.2370x over previous
//
#include <hip/hip_runtime.h>
#include <hip/hip_bf16.h>
#include <math.h>

#define N_  128
#define D_  512
#define L_  512
#define K_  512
#define KH_ 256       // mirror symmetry: out[..,k] == out[..,511-k]
#define M_  (N_*D_)   // 65536

typedef __bf16 bf16x8 __attribute__((ext_vector_type(8)));
typedef float  f32x4  __attribute__((ext_vector_type(4)));
typedef unsigned short ushort_t;

// ---------------------------------------------------------------------------
// Kernel 1: bf16 DFT basis for k = 0..255 ONLY (exact mirror symmetry:
// ang(l,511-k) = 2*pi*l - ang(l,k) for integer l => cos equal, sin negated,
// so |X[...,511-k]| == |X[...,k]| exactly). Plus separable window tables:
// P=a*e, Q=-(1-a)*e, e=exp(sigma/511), C[l]=cos(2*pi*l/511).
// ---------------------------------------------------------------------------
__global__ void basis_kernel(const float* __restrict__ a,
                             const float* __restrict__ sigma,
                             ushort_t* __restrict__ Bc,
                             ushort_t* __restrict__ Bs,
                             float* __restrict__ P,
                             float* __restrict__ Q,
                             float* __restrict__ C) {
    int idx = blockIdx.x * 256 + threadIdx.x;   // 0 .. 256*512-1
    int r = idx >> 9;    // k (0..255)
    int c = idx & 511;   // l
    unsigned m = (unsigned)(r * c) % 511u;      // exact periodic reduction
    const float w0 = 6.283185307179586f / 511.0f;
    float sn, cs;
    sincosf((float)m * w0, &sn, &cs);
    __hip_bfloat16 bc = __float2bfloat16(cs);
    __hip_bfloat16 bs = __float2bfloat16(sn);
    ushort_t uc, us;
    __builtin_memcpy(&uc, &bc, 2);
    __builtin_memcpy(&us, &bs, 2);
    Bc[idx] = uc;
    Bs[idx] = us;
    if (idx < 512) {
        float e = expf(sigma[idx] * (1.0f / 511.0f));
        P[idx] = a[idx] * e;
        Q[idx] = -(1.0f - a[idx]) * e;
        C[idx] = cosf((float)idx * w0);
    }
}

static __device__ __forceinline__ unsigned pack_bf16x2(float lo, float hi) {
    __hip_bfloat162 h = __float22bfloat162_rn(make_float2(lo, hi));
    unsigned u;
    __builtin_memcpy(&u, &h, 4);
    return u;   // lo in low 16 bits -> memory order [lo, hi]
}

static __device__ __forceinline__ void load_lds_128(const void* g, void* l) {
    __builtin_amdgcn_global_load_lds(
        (const __attribute__((address_space(1))) unsigned int*)g,
        (__attribute__((address_space(3))) unsigned int*)l,
        16, 0, 0);
}

// ---------------------------------------------------------------------------
// Kernel 2 (FUSED + HALVED): prep folded into A-staging; GEMM computes only
// output columns 0..255, epilogue writes each value to col and 511-col.
// 1024 blocks (mg 0..511 x ng 0..1), per-block structure unchanged from r2.
// ---------------------------------------------------------------------------
__global__ __launch_bounds__(256, 2)
void dft_gemm5(const float* __restrict__ x,
               const ushort_t* __restrict__ Bc,
               const ushort_t* __restrict__ Bs,
               const float* __restrict__ P,
               const float* __restrict__ Q,
               const float* __restrict__ C,
               float* __restrict__ out) {
    // [2] double buffers, each 128x32 bf16 = 8 KB -> 48 KB total
    __shared__ ushort_t sA [2 * 128 * 32];
    __shared__ ushort_t sBc[2 * 128 * 32];
    __shared__ ushort_t sBs[2 * 128 * 32];

    // XCD-chunked bijection (1024 = 8 * 128, evenly divisible -> safe):
    // consecutive wg on the same XCD -> the 2 N-siblings of an A-panel share L2.
    const int bhw = blockIdx.x;
    const int wg  = (bhw & 7) * 128 + (bhw >> 3);
    const int ng  = wg & 1;
    const int mg  = wg >> 1;
    const int m0  = mg * 128;
    const int n0  = ng * 128;

    const int tid  = threadIdx.x;
    const int w    = tid >> 6;
    const int lane = tid & 63;

    // ---- A fused staging mapping: thread -> rows r0, r0+64, k-chunk c ----
    const int ar0 = tid >> 2;                 // 0..63
    const int ac  = tid & 3;                  // logical 8-elem k-chunk
    const int ar1 = ar0 + 64;
    const int apc = ac ^ ((ar0 >> 1) & 3);    // phys chunk (same for ar1)
    const int d0  = m0 & (D_ - 1);

    const float p0 = P[d0 + ar0], q0 = Q[d0 + ar0];
    const float p1 = P[d0 + ar1], q1 = Q[d0 + ar1];

    const float* xr0 = x + (size_t)(m0 + ar0) * L_ + ac * 8;
    const float* xr1 = x + (size_t)(m0 + ar1) * L_ + ac * 8;
    const float* Cc  = C + ac * 8;

    ushort_t* aD0 = sA + ar0 * 32 + apc * 8;  // + buf*4096
    ushort_t* aD1 = sA + ar1 * 32 + apc * 8;

    // ---- B staging via global_load_lds (pre-swizzled per-lane source) ----
    const int br0 = tid >> 2;
    const int bq0 = (tid & 3) ^ ((br0 >> 1) & 3);
    const int br1 = (256 + tid) >> 2;
    const int bq1 = ((256 + tid) & 3) ^ ((br1 >> 1) & 3);

    const ushort_t* bcS0 = Bc + (size_t)(n0 + br0) * L_ + bq0 * 8;
    const ushort_t* bcS1 = Bc + (size_t)(n0 + br1) * L_ + bq1 * 8;
    const ushort_t* bsS0 = Bs + (size_t)(n0 + br0) * L_ + bq0 * 8;
    const ushort_t* bsS1 = Bs + (size_t)(n0 + br1) * L_ + bq1 * 8;

    const int wm = w >> 1, wn = w & 1;
    const int ml = lane & 15, quad = lane >> 4;

    int aOff[4], bOff[4];
#pragma unroll
    for (int mi = 0; mi < 4; ++mi) {
        int ar = wm * 64 + mi * 16 + ml;
        int pc = quad ^ ((ar >> 1) & 3);
        aOff[mi] = ar * 32 + pc * 8;
    }
#pragma unroll
    for (int ni = 0; ni < 4; ++ni) {
        int br = wn * 64 + ni * 16 + ml;
        int pc = quad ^ ((br >> 1) & 3);
        bOff[ni] = br * 32 + pc * 8;
    }

    f32x4 acc_c[4][4], acc_s[4][4];
    const f32x4 zero = {0.f, 0.f, 0.f, 0.f};
#pragma unroll
    for (int mi = 0; mi < 4; ++mi)
#pragma unroll
        for (int ni = 0; ni < 4; ++ni) { acc_c[mi][ni] = zero; acc_s[mi][ni] = zero; }

#define STAGE_B(buf, kk)                                                      \
    do {                                                                      \
        const int bo_ = (buf) * 4096;                                         \
        load_lds_128(bcS0 + (kk), sBc + bo_ + w * 512);                       \
        load_lds_128(bcS1 + (kk), sBc + bo_ + 2048 + w * 512);                \
        load_lds_128(bsS0 + (kk), sBs + bo_ + w * 512);                       \
        load_lds_128(bsS1 + (kk), sBs + bo_ + 2048 + w * 512);                \
    } while (0)

    // window + bf16-pack + swizzled ds_write of one A k-tile (2 rows/thread)
    auto writeA = [&](int buf, float4 v00, float4 v01, float4 v10, float4 v11,
                      float4 cv0, float4 cv1) {
        int bo = buf * 4096;
        // row ar0
        float w0a = fmaf(q0, cv0.x, p0), w0b = fmaf(q0, cv0.y, p0);
        float w0c = fmaf(q0, cv0.z, p0), w0d = fmaf(q0, cv0.w, p0);
        float w0e = fmaf(q0, cv1.x, p0), w0f = fmaf(q0, cv1.y, p0);
        float w0g = fmaf(q0, cv1.z, p0), w0h = fmaf(q0, cv1.w, p0);
        int4 s0;
        s0.x = (int)pack_bf16x2(v00.x * w0a, v00.y * w0b);
        s0.y = (int)pack_bf16x2(v00.z * w0c, v00.w * w0d);
        s0.z = (int)pack_bf16x2(v01.x * w0e, v01.y * w0f);
        s0.w = (int)pack_bf16x2(v01.z * w0g, v01.w * w0h);
        *(int4*)(aD0 + bo) = s0;
        // row ar1
        float w1a = fmaf(q1, cv0.x, p1), w1b = fmaf(q1, cv0.y, p1);
        float w1c = fmaf(q1, cv0.z, p1), w1d = fmaf(q1, cv0.w, p1);
        float w1e = fmaf(q1, cv1.x, p1), w1f = fmaf(q1, cv1.y, p1);
        float w1g = fmaf(q1, cv1.z, p1), w1h = fmaf(q1, cv1.w, p1);
        int4 s1;
        s1.x = (int)pack_bf16x2(v10.x * w1a, v10.y * w1b);
        s1.y = (int)pack_bf16x2(v10.z * w1c, v10.w * w1d);
        s1.z = (int)pack_bf16x2(v11.x * w1e, v11.y * w1f);
        s1.w = (int)pack_bf16x2(v11.z * w1g, v11.w * w1h);
        *(int4*)(aD1 + bo) = s1;
    };

    auto compute_tile = [&](int buf) {
        const int bo = buf * 4096;
        bf16x8 af[4], bcf[4], bsf[4];
#pragma unroll
        for (int mi = 0; mi < 4; ++mi)
            af[mi] = *(const bf16x8*)&sA[bo + aOff[mi]];
#pragma unroll
        for (int ni = 0; ni < 4; ++ni) {
            bcf[ni] = *(const bf16x8*)&sBc[bo + bOff[ni]];
            bsf[ni] = *(const bf16x8*)&sBs[bo + bOff[ni]];
        }
#pragma unroll
        for (int mi = 0; mi < 4; ++mi)
#pragma unroll
            for (int ni = 0; ni < 4; ++ni) {
                acc_c[mi][ni] = __builtin_amdgcn_mfma_f32_16x16x32_bf16(
                    af[mi], bcf[ni], acc_c[mi][ni], 0, 0, 0);
                acc_s[mi][ni] = __builtin_amdgcn_mfma_f32_16x16x32_bf16(
                    af[mi], bsf[ni], acc_s[mi][ni], 0, 0, 0);
            }
    };

    // ---- prologue: tile 0 -> buf 0 ----
    float4 a00 = *(const float4*)(xr0 + 0);
    float4 a01 = *(const float4*)(xr0 + 4);
    float4 a10 = *(const float4*)(xr1 + 0);
    float4 a11 = *(const float4*)(xr1 + 4);
    float4 cv0 = *(const float4*)(Cc + 0);
    float4 cv1 = *(const float4*)(Cc + 4);
    STAGE_B(0, 0);
    writeA(0, a00, a01, a10, a11, cv0, cv1);
    __syncthreads();

    int cur = 0;
    for (int kk = 32; kk < L_; kk += 32) {
        // issue next-tile A loads FIRST (latency hides under MFMA phase)
        a00 = *(const float4*)(xr0 + kk);
        a01 = *(const float4*)(xr0 + kk + 4);
        a10 = *(const float4*)(xr1 + kk);
        a11 = *(const float4*)(xr1 + kk + 4);
        cv0 = *(const float4*)(Cc + kk);
        cv1 = *(const float4*)(Cc + kk + 4);
        STAGE_B(cur ^ 1, kk);       // B loads for next tile (vmcnt, async)
        compute_tile(cur);          // ds_read + 32 MFMA on current buffer
        writeA(cur ^ 1, a00, a01, a10, a11, cv0, cv1);  // write-late (T14)
        __syncthreads();            // drains vmcnt + lgkm; buffers swap
        cur ^= 1;
    }
    compute_tile(cur);              // last k-tile

#undef STAGE_B

    // C/D layout: col = lane&15, row = quad*4 + reg (m89/m91-verified)
    // Mirror write: |X[row][511-col]| == |X[row][col]| exactly.
#pragma unroll
    for (int mi = 0; mi < 4; ++mi)
#pragma unroll
        for (int ni = 0; ni < 4; ++ni) {
#pragma unroll
            for (int r = 0; r < 4; ++r) {
                float cv = acc_c[mi][ni][r];
                float sv = acc_s[mi][ni][r];
                int row = m0 + wm * 64 + mi * 16 + quad * 4 + r;
                int col = n0 + wn * 64 + ni * 16 + ml;
                float v = sqrtf(cv * cv + sv * sv);
                out[(size_t)row * K_ + col] = v;
                out[(size_t)row * K_ + (K_ - 1 - col)] = v;
            }
        }
}

extern "C" void kernel_launch(void* const* d_in, const int* in_sizes, int n_in,
                              void* d_out, int out_size, void* d_ws, size_t ws_size,
                              hipStream_t stream) {
    (void)in_sizes; (void)n_in; (void)out_size; (void)ws_size;
    const float* x     = (const float*)d_in[0];
    const float* a     = (const float*)d_in[1];
    const float* sigma = (const float*)d_in[2];
    float* out = (float*)d_out;

    // ws: Bc (256KB) | Bs (256KB) | P (2KB) | Q (2KB) | C (2KB)
    ushort_t* Bc = (ushort_t*)d_ws;
    ushort_t* Bs = Bc + KH_ * 512;
    float*    P  = (float*)(Bs + KH_ * 512);
    float*    Q  = P + 512;
    float*    C  = Q + 512;

    basis_kernel<<<dim3(512), dim3(256), 0, stream>>>(a, sigma, Bc, Bs, P, Q, C);
    dft_gemm5<<<dim3(1024), dim3(256), 0, stream>>>(x, Bc, Bs, P, Q, C, out);
}